// Round 5
// baseline (173.733 us; speedup 1.0000x reference)
//
#include <hip/hip_runtime.h>
#include <hip/hip_bf16.h>

// Problem constants (from reference)
#define PCR0   (-51.2f)
#define PCR1   (-51.2f)
#define VX_    (0.05f)
#define VY_    (0.05f)
#define STRIDE_ 4.0f
#define FW_    512
#define FH_    512
#define NCLS   10
#define NOBJ   500
#define OVERLAP_ 0.1f
#define MINRAD 2
#define RMAX_  16
#define BATCH_ 16
#define EPS_   1.1920928955078125e-07f   // np.finfo(float32).eps

// Flat output layout (all stored as float32 elements)
#define HEATMAP_ELEMS  (BATCH_ * NCLS * FH_ * FW_)       // 41,943,040
#define RETBOX_OFF     HEATMAP_ELEMS
#define RETBOX_ELEMS   (BATCH_ * NOBJ * 8)               // 64,000
#define INDS_OFF       (RETBOX_OFF + RETBOX_ELEMS)       // 42,007,040
#define MASK_OFF       (INDS_OFF + BATCH_ * NOBJ)        // 42,015,040

// One block per (batch, 32-row band); block loops over the 10 classes.
#define BAND_  32
#define NBAND  (FH_ / BAND_)                 // 16
#define NBLOCK (BATCH_ * NBAND)              // 256 == CU count

// ---------------------------------------------------------------------------
// Per-object math (identical arithmetic to rounds 1-4 so truncation
// boundaries don't move).
// ---------------------------------------------------------------------------
__device__ __forceinline__ void obj_params(const float* g8,
        float& coord_x, float& coord_y, int& cxi, int& cyi,
        int& radius, bool& valid)
{
    const float x = g8[0], y = g8[1];
    const float dx = g8[3], dy = g8[4];

    coord_x = fminf(fmaxf((x - PCR0) / VX_ / STRIDE_, 0.f), (float)FW_ - 0.5f);
    coord_y = fminf(fmaxf((y - PCR1) / VY_ / STRIDE_, 0.f), (float)FH_ - 0.5f);
    cxi = (int)coord_x;
    cyi = (int)coord_y;

    float dxf = dx / VX_ / STRIDE_;
    float dyf = dy / VY_ / STRIDE_;

    const float h = dxf, w = dyf, o = OVERLAP_;
    float b1 = h + w;
    float c1 = w * h * (1.f - o) / (1.f + o);
    float r1 = (b1 + sqrtf(fmaxf(b1 * b1 - 4.f * c1, 0.f))) * 0.5f;
    float b2 = 2.f * (h + w);
    float c2 = (1.f - o) * w * h;
    float r2 = (b2 + sqrtf(fmaxf(b2 * b2 - 16.f * c2, 0.f))) * 0.5f;
    float a3 = 4.f * o;
    float b3 = -2.f * o * (h + w);
    float c3 = (o - 1.f) * w * h;
    float r3 = (b3 + sqrtf(fmaxf(b3 * b3 - 4.f * a3 * c3, 0.f))) / (2.f * a3);
    float radf = fminf(fminf(r1, r2), r3);
    radius = (int)radf;
    radius = min(max(radius, MINRAD), RMAX_);

    valid = (dxf > 0.f) && (dyf > 0.f) &&
            (cxi >= 0) && (cxi <= FW_) && (cyi >= 0) && (cyi <= FH_);
}

// ---------------------------------------------------------------------------
// Single fused kernel. One 1024-thread block per (batch, band):
//   1) threads 0..499 scan the batch's objects ONCE; per-object outputs are
//      written by the band==0 block of each batch; band-overlapping objects
//      are bucketed into per-class segments of an LDS record array
//      (count -> prefix -> place).
//   2) for each class c: gather max over segment c (separable gaussian,
//      wave-uniform early-outs), store the contiguous 64 KB slab once.
// Stores pipeline across class iterations (no dependent waits), so the
// kernel approaches the pure store bound.
// ---------------------------------------------------------------------------
__global__ __launch_bounds__(1024) void fused(
        const float* __restrict__ gt, float* __restrict__ out)
{
    const int bid  = blockIdx.x;                 // 0 .. NBLOCK-1
    const int b    = bid >> 4;                   // batch
    const int band = bid & (NBAND - 1);
    const int y0   = band << 5;

    __shared__ int  s_cnt[NCLS];                 // per-class counts
    __shared__ int  s_pos[NCLS];                 // per-class placement cursors
    __shared__ int  s_off[NCLS];                 // per-class segment offsets
    __shared__ int4 s_rec[NOBJ];                 // bucketed records

    const int t = threadIdx.x;
    if (t < NCLS) { s_cnt[t] = 0; s_pos[t] = 0; }
    __syncthreads();

    // -------- pass 1: scan + count --------
    bool mine = false; int myc = 0; int4 myrec;
    if (t < NOBJ) {
        const int obj = b * NOBJ + t;
        const float* g8 = gt + (size_t)obj * 8;
        float coord_x, coord_y; int cxi, cyi, radius; bool valid;
        obj_params(g8, coord_x, coord_y, cxi, cyi, radius, valid);
        int c = min(max((int)(g8[7] - 1.0f), 0), NCLS - 1);

        if (band == 0) {
            // designated writer block for this batch: per-object outputs
            const float z = g8[2], dx = g8[3], dy = g8[4], dz = g8[5];
            const float hd = g8[6];
            float vf = valid ? 1.f : 0.f;
            float* rb = out + RETBOX_OFF + (size_t)obj * 8;
            rb[0] = (coord_x - (float)cxi) * vf;
            rb[1] = (coord_y - (float)cyi) * vf;
            rb[2] = z * vf;
            rb[3] = logf(fmaxf(dx, 1e-12f)) * vf;
            rb[4] = logf(fmaxf(dy, 1e-12f)) * vf;
            rb[5] = logf(fmaxf(dz, 1e-12f)) * vf;
            rb[6] = cosf(hd) * vf;
            rb[7] = sinf(hd) * vf;
            out[INDS_OFF + obj] = valid ? (float)(cyi * FW_ + cxi) : 0.f;
            out[MASK_OFF + obj] = vf;
        }

        if (valid && (cyi + radius >= y0) && (cyi - radius <= y0 + BAND_ - 1)) {
            float sigma = (2.f * (float)radius + 1.f) / 6.f;
            float negInv = -1.0f / (2.f * sigma * sigma);
            mine = true; myc = c;
            myrec = make_int4(cxi, cyi, radius, __float_as_int(negInv));
            atomicAdd(&s_cnt[c], 1);
        }
    }
    __syncthreads();

    // -------- prefix over 10 classes --------
    if (t == 0) {
        int a = 0;
        #pragma unroll
        for (int c = 0; c < NCLS; ++c) { s_off[c] = a; a += s_cnt[c]; }
    }
    __syncthreads();

    // -------- pass 2: place records --------
    if (mine) {
        int p = atomicAdd(&s_pos[myc], 1);
        s_rec[s_off[myc] + p] = myrec;
    }
    __syncthreads();

    // -------- gather + store, one class at a time --------
    const int col0  = (t & 127) << 2;                                  // 0..508
    const int r0    = __builtin_amdgcn_readfirstlane(t >> 7);          // 0..7
    const int wbase = __builtin_amdgcn_readfirstlane(((t >> 6) & 1) << 8); // 0 or 256

    const size_t plane = (size_t)FH_ * FW_;

    for (int c = 0; c < NCLS; ++c) {
        const int n   = __builtin_amdgcn_readfirstlane(s_cnt[c]);
        const int off = __builtin_amdgcn_readfirstlane(s_off[c]);

        float acc[4][4];
        #pragma unroll
        for (int s = 0; s < 4; ++s) {
            acc[s][0] = 0.f; acc[s][1] = 0.f; acc[s][2] = 0.f; acc[s][3] = 0.f;
        }

        for (int it = 0; it < n; ++it) {
            int4 r = s_rec[off + it];            // broadcast LDS read
            int cxi   = __builtin_amdgcn_readfirstlane(r.x);
            int cyi   = __builtin_amdgcn_readfirstlane(r.y);
            int rad   = __builtin_amdgcn_readfirstlane(r.z);
            float negInv = __int_as_float(__builtin_amdgcn_readfirstlane(r.w));

            // wave-uniform column-range early-out (wave covers [wbase, wbase+255])
            if (cxi + rad < wbase || cxi - rad > wbase + 255) continue;

            float cexp[4]; bool colin[4];
            #pragma unroll
            for (int k = 0; k < 4; ++k) {
                int rx = col0 + k - cxi;
                colin[k] = (rx >= -rad) && (rx <= rad);
                cexp[k]  = __expf((float)(rx * rx) * negInv);
            }

            #pragma unroll
            for (int s = 0; s < 4; ++s) {
                int ry = y0 + 8 * s + r0 - cyi;      // wave-uniform
                if (ry < -rad || ry > rad) continue; // scalar branch
                float rexp = __expf((float)(ry * ry) * negInv);
                #pragma unroll
                for (int k = 0; k < 4; ++k) {
                    float g = rexp * cexp[k];
                    bool ok = colin[k] && (g >= EPS_);
                    acc[s][k] = ok ? fmaxf(acc[s][k], g) : acc[s][k];
                }
            }
        }

        // contiguous 64 KB slab store for this class
        float4* out4 = (float4*)(out + ((size_t)(b * NCLS + c)) * plane
                                     + (size_t)y0 * FW_);
        #pragma unroll
        for (int s = 0; s < 4; ++s)
            out4[s * 1024 + t] = make_float4(acc[s][0], acc[s][1], acc[s][2], acc[s][3]);
    }
}

extern "C" void kernel_launch(void* const* d_in, const int* in_sizes, int n_in,
                              void* d_out, int out_size, void* d_ws, size_t ws_size,
                              hipStream_t stream) {
    const float* gt = (const float*)d_in[0];
    float* out = (float*)d_out;
    fused<<<NBLOCK, 1024, 0, stream>>>(gt, out);
}

// Round 6
// 168.031 us; speedup vs baseline: 1.0339x; 1.0339x over previous
//
#include <hip/hip_runtime.h>
#include <hip/hip_bf16.h>

// Problem constants (from reference)
#define PCR0   (-51.2f)
#define PCR1   (-51.2f)
#define VX_    (0.05f)
#define VY_    (0.05f)
#define STRIDE_ 4.0f
#define FW_    512
#define FH_    512
#define NCLS   10
#define NOBJ   500
#define OVERLAP_ 0.1f
#define MINRAD 2
#define RMAX_  16
#define BATCH_ 16
#define EPS_   1.1920928955078125e-07f   // np.finfo(float32).eps

// Flat output layout (all stored as float32 elements)
#define HEATMAP_ELEMS  (BATCH_ * NCLS * FH_ * FW_)       // 41,943,040
#define RETBOX_OFF     HEATMAP_ELEMS
#define RETBOX_ELEMS   (BATCH_ * NOBJ * 8)               // 64,000
#define INDS_OFF       (RETBOX_OFF + RETBOX_ELEMS)       // 42,007,040
#define MASK_OFF       (INDS_OFF + BATCH_ * NOBJ)        // 42,015,040

// Bins: (class, 32-row band) per batch. Slab = contiguous 64 KB.
#define BAND_  32
#define NBAND  (FH_ / BAND_)                 // 16
#define BIN_N  (NCLS * NBAND)                // 160 bins per batch
#define NBINS  (BATCH_ * BIN_N)              // 2560 blocks for phaseB
#define RECMAX 1000                          // 500 objs x <=2 bands each

// ws layout: per batch: cnt[160], off[160], rec[1000] (int4)
#define BSTRIDE     (2 * BIN_N + RECMAX * 4)             // ints per batch = 4320
#define WS_NEEDED   ((size_t)BATCH_ * BSTRIDE * 4)       // 276,480 B

// ---------------------------------------------------------------------------
// Per-object math (identical arithmetic to rounds 1-5 so truncation
// boundaries don't move).
// ---------------------------------------------------------------------------
__device__ __forceinline__ void obj_params(const float* g8,
        float& coord_x, float& coord_y, int& cxi, int& cyi,
        int& radius, bool& valid)
{
    const float x = g8[0], y = g8[1];
    const float dx = g8[3], dy = g8[4];

    coord_x = fminf(fmaxf((x - PCR0) / VX_ / STRIDE_, 0.f), (float)FW_ - 0.5f);
    coord_y = fminf(fmaxf((y - PCR1) / VY_ / STRIDE_, 0.f), (float)FH_ - 0.5f);
    cxi = (int)coord_x;
    cyi = (int)coord_y;

    float dxf = dx / VX_ / STRIDE_;
    float dyf = dy / VY_ / STRIDE_;

    const float h = dxf, w = dyf, o = OVERLAP_;
    float b1 = h + w;
    float c1 = w * h * (1.f - o) / (1.f + o);
    float r1 = (b1 + sqrtf(fmaxf(b1 * b1 - 4.f * c1, 0.f))) * 0.5f;
    float b2 = 2.f * (h + w);
    float c2 = (1.f - o) * w * h;
    float r2 = (b2 + sqrtf(fmaxf(b2 * b2 - 16.f * c2, 0.f))) * 0.5f;
    float a3 = 4.f * o;
    float b3 = -2.f * o * (h + w);
    float c3 = (o - 1.f) * w * h;
    float r3 = (b3 + sqrtf(fmaxf(b3 * b3 - 4.f * a3 * c3, 0.f))) / (2.f * a3);
    float radf = fminf(fminf(r1, r2), r3);
    radius = (int)radf;
    radius = min(max(radius, MINRAD), RMAX_);

    valid = (dxf > 0.f) && (dyf > 0.f) &&
            (cxi >= 0) && (cxi <= FW_) && (cyi >= 0) && (cyi <= FH_);
}

// ---------------------------------------------------------------------------
// Phase A: one block per batch (16 blocks x 512). Scans the batch ONCE:
// writes ret_boxes/inds/mask, buckets records into per-(class,band) compact
// segments in LDS (count -> prefix -> place), streams cnt/off/rec to ws.
// ---------------------------------------------------------------------------
__global__ __launch_bounds__(512) void phaseA(
        const float* __restrict__ gt, float* __restrict__ out,
        int* __restrict__ bins)
{
    const int b = blockIdx.x;
    const int t = threadIdx.x;

    __shared__ int  s_cnt[BIN_N], s_off[BIN_N], s_pos[BIN_N];
    __shared__ int4 s_rec[RECMAX];

    if (t < BIN_N) { s_cnt[t] = 0; s_pos[t] = 0; }
    __syncthreads();

    bool valid = false; int c = 0, ty0 = 0, ty1 = -1; int4 rec;
    if (t < NOBJ) {
        const int obj = b * NOBJ + t;
        const float* g8 = gt + (size_t)obj * 8;
        float coord_x, coord_y; int cxi, cyi, radius;
        obj_params(g8, coord_x, coord_y, cxi, cyi, radius, valid);
        c = min(max((int)(g8[7] - 1.0f), 0), NCLS - 1);

        // per-object outputs
        const float z = g8[2], dx = g8[3], dy = g8[4], dz = g8[5];
        const float hd = g8[6];
        float vf = valid ? 1.f : 0.f;
        float* rb = out + RETBOX_OFF + (size_t)obj * 8;
        rb[0] = (coord_x - (float)cxi) * vf;
        rb[1] = (coord_y - (float)cyi) * vf;
        rb[2] = z * vf;
        rb[3] = logf(fmaxf(dx, 1e-12f)) * vf;
        rb[4] = logf(fmaxf(dy, 1e-12f)) * vf;
        rb[5] = logf(fmaxf(dz, 1e-12f)) * vf;
        rb[6] = cosf(hd) * vf;
        rb[7] = sinf(hd) * vf;
        out[INDS_OFF + obj] = valid ? (float)(cyi * FW_ + cxi) : 0.f;
        out[MASK_OFF + obj] = vf;

        if (valid) {
            float sigma = (2.f * (float)radius + 1.f) / 6.f;
            float negInv = -1.0f / (2.f * sigma * sigma);
            rec = make_int4(cxi, cyi, radius, __float_as_int(negInv));
            ty0 = max(cyi - radius, 0) >> 5;
            ty1 = min(cyi + radius, FH_ - 1) >> 5;   // ty1 <= ty0+1 (33 rows)
            for (int ty = ty0; ty <= ty1; ++ty)
                atomicAdd(&s_cnt[c * NBAND + ty], 1);
        }
    }
    __syncthreads();

    if (t == 0) {
        int a = 0;
        for (int i = 0; i < BIN_N; ++i) { s_off[i] = a; a += s_cnt[i]; }
    }
    __syncthreads();

    if (valid) {
        for (int ty = ty0; ty <= ty1; ++ty) {
            int bin = c * NBAND + ty;
            int p = atomicAdd(&s_pos[bin], 1);
            s_rec[s_off[bin] + p] = rec;
        }
    }
    __syncthreads();

    int* g = bins + b * BSTRIDE;
    for (int i = t; i < BIN_N; i += 512) { g[i] = s_cnt[i]; g[BIN_N + i] = s_off[i]; }
    const int total = s_off[BIN_N - 1] + s_cnt[BIN_N - 1];
    int4* gr = (int4*)(g + 2 * BIN_N);               // 16B-aligned
    for (int i = t; i < total; i += 512) gr[i] = s_rec[i];
}

// ---------------------------------------------------------------------------
// Phase B: one 512-thread block per (batch, class, band) slab. Prologue is
// TWO scalar loads; no LDS, no barrier, no atomics. Gather max over the
// bin's compact records (L2-hot), store the contiguous 64 KB slab once.
// blockIdx.x IS the linear slab index, so stores stream sequentially.
// ---------------------------------------------------------------------------
__global__ __launch_bounds__(512) void phaseB(
        float* __restrict__ out, const int* __restrict__ bins)
{
    const int bid = blockIdx.x;                 // 0 .. NBINS-1
    const int b   = bid / BIN_N;
    const int rem = bid - b * BIN_N;            // c*NBAND + band
    const int y0  = (rem & (NBAND - 1)) << 5;
    const int t   = threadIdx.x;

    const int* g = bins + b * BSTRIDE;
    const int n   = __builtin_amdgcn_readfirstlane(g[rem]);
    const int off = __builtin_amdgcn_readfirstlane(g[BIN_N + rem]);
    const int4* rec = (const int4*)(g + 2 * BIN_N);

    const int col0  = (t & 127) << 2;                                  // 0..508
    const int r0    = __builtin_amdgcn_readfirstlane(t >> 7);          // 0..3
    const int wbase = __builtin_amdgcn_readfirstlane(((t >> 6) & 1) << 8); // 0 or 256

    float acc[8][4];
    #pragma unroll
    for (int s = 0; s < 8; ++s) {
        acc[s][0] = 0.f; acc[s][1] = 0.f; acc[s][2] = 0.f; acc[s][3] = 0.f;
    }

    for (int it = 0; it < n; ++it) {
        int4 r = rec[off + it];
        int cxi   = __builtin_amdgcn_readfirstlane(r.x);
        int cyi   = __builtin_amdgcn_readfirstlane(r.y);
        int rad   = __builtin_amdgcn_readfirstlane(r.z);
        float negInv = __int_as_float(__builtin_amdgcn_readfirstlane(r.w));

        // wave-uniform column-range early-out (wave covers [wbase, wbase+255])
        if (cxi + rad < wbase || cxi - rad > wbase + 255) continue;

        float cexp[4]; bool colin[4];
        #pragma unroll
        for (int k = 0; k < 4; ++k) {
            int rx = col0 + k - cxi;
            colin[k] = (rx >= -rad) && (rx <= rad);
            cexp[k]  = __expf((float)(rx * rx) * negInv);
        }

        #pragma unroll
        for (int s = 0; s < 8; ++s) {
            int ry = y0 + 4 * s + r0 - cyi;      // wave-uniform
            if (ry < -rad || ry > rad) continue; // scalar branch
            float rexp = __expf((float)(ry * ry) * negInv);
            #pragma unroll
            for (int k = 0; k < 4; ++k) {
                float gg = rexp * cexp[k];
                bool ok = colin[k] && (gg >= EPS_);
                acc[s][k] = ok ? fmaxf(acc[s][k], gg) : acc[s][k];
            }
        }
    }

    // contiguous 64 KB slab store; blockIdx order == memory order
    float4* out4 = (float4*)(out + (size_t)bid * (BAND_ * FW_));
    #pragma unroll
    for (int s = 0; s < 8; ++s)
        out4[s * 512 + t] = make_float4(acc[s][0], acc[s][1], acc[s][2], acc[s][3]);
}

// ---------------------------------------------------------------------------
// Fallback (R4 fused kernel, known-correct) if ws is too small.
// ---------------------------------------------------------------------------
__global__ __launch_bounds__(512) void fused(
        const float* __restrict__ gt, float* __restrict__ out)
{
    const int bid  = blockIdx.x;
    const int b    = bid / (NCLS * NBAND);
    const int rem  = bid - b * (NCLS * NBAND);
    const int myc  = rem >> 4;
    const int band = rem & (NBAND - 1);
    const int y0   = band << 5;

    __shared__ int  s_cnt;
    __shared__ int4 s_rec[NOBJ];

    if (threadIdx.x == 0) s_cnt = 0;
    __syncthreads();

    const int t = threadIdx.x;
    if (t < NOBJ) {
        const int obj = b * NOBJ + t;
        const float* g8 = gt + (size_t)obj * 8;
        float coord_x, coord_y; int cxi, cyi, radius; bool valid;
        obj_params(g8, coord_x, coord_y, cxi, cyi, radius, valid);
        int c = min(max((int)(g8[7] - 1.0f), 0), NCLS - 1);

        if (myc == 0 && band == 0) {
            const float z = g8[2], dx = g8[3], dy = g8[4], dz = g8[5];
            const float hd = g8[6];
            float vf = valid ? 1.f : 0.f;
            float* rb = out + RETBOX_OFF + (size_t)obj * 8;
            rb[0] = (coord_x - (float)cxi) * vf;
            rb[1] = (coord_y - (float)cyi) * vf;
            rb[2] = z * vf;
            rb[3] = logf(fmaxf(dx, 1e-12f)) * vf;
            rb[4] = logf(fmaxf(dy, 1e-12f)) * vf;
            rb[5] = logf(fmaxf(dz, 1e-12f)) * vf;
            rb[6] = cosf(hd) * vf;
            rb[7] = sinf(hd) * vf;
            out[INDS_OFF + obj] = valid ? (float)(cyi * FW_ + cxi) : 0.f;
            out[MASK_OFF + obj] = vf;
        }

        if (valid && c == myc &&
            (cyi + radius >= y0) && (cyi - radius <= y0 + BAND_ - 1)) {
            float sigma = (2.f * (float)radius + 1.f) / 6.f;
            float negInv = -1.0f / (2.f * sigma * sigma);
            int pos = atomicAdd(&s_cnt, 1);
            s_rec[pos] = make_int4(cxi, cyi, radius, __float_as_int(negInv));
        }
    }
    __syncthreads();

    const int col0  = (t & 127) << 2;
    const int r0    = __builtin_amdgcn_readfirstlane(t >> 7);
    const int wbase = __builtin_amdgcn_readfirstlane(((t >> 6) & 1) << 8);

    float acc[8][4];
    #pragma unroll
    for (int s = 0; s < 8; ++s) {
        acc[s][0] = 0.f; acc[s][1] = 0.f; acc[s][2] = 0.f; acc[s][3] = 0.f;
    }

    const int n = s_cnt;
    for (int it = 0; it < n; ++it) {
        int4 r = s_rec[it];
        int cxi   = __builtin_amdgcn_readfirstlane(r.x);
        int cyi   = __builtin_amdgcn_readfirstlane(r.y);
        int rad   = __builtin_amdgcn_readfirstlane(r.z);
        float negInv = __int_as_float(__builtin_amdgcn_readfirstlane(r.w));

        if (cxi + rad < wbase || cxi - rad > wbase + 255) continue;

        float cexp[4]; bool colin[4];
        #pragma unroll
        for (int k = 0; k < 4; ++k) {
            int rx = col0 + k - cxi;
            colin[k] = (rx >= -rad) && (rx <= rad);
            cexp[k]  = __expf((float)(rx * rx) * negInv);
        }

        #pragma unroll
        for (int s = 0; s < 8; ++s) {
            int ry = y0 + 4 * s + r0 - cyi;
            if (ry < -rad || ry > rad) continue;
            float rexp = __expf((float)(ry * ry) * negInv);
            #pragma unroll
            for (int k = 0; k < 4; ++k) {
                float gg = rexp * cexp[k];
                bool ok = colin[k] && (gg >= EPS_);
                acc[s][k] = ok ? fmaxf(acc[s][k], gg) : acc[s][k];
            }
        }
    }

    float4* out4 = (float4*)(out + (size_t)bid * (BAND_ * FW_));
    #pragma unroll
    for (int s = 0; s < 8; ++s)
        out4[s * 512 + t] = make_float4(acc[s][0], acc[s][1], acc[s][2], acc[s][3]);
}

extern "C" void kernel_launch(void* const* d_in, const int* in_sizes, int n_in,
                              void* d_out, int out_size, void* d_ws, size_t ws_size,
                              hipStream_t stream) {
    const float* gt = (const float*)d_in[0];
    float* out = (float*)d_out;

    if (ws_size >= WS_NEEDED) {
        int* bins = (int*)d_ws;
        phaseA<<<BATCH_, 512, 0, stream>>>(gt, out, bins);
        phaseB<<<NBINS, 512, 0, stream>>>(out, bins);
    } else {
        fused<<<NBINS, 512, 0, stream>>>(gt, out);
    }
}